// Round 2
// baseline (780.853 us; speedup 1.0000x reference)
//
#include <hip/hip_runtime.h>
#include <hip/hip_bf16.h>

// EAConv: EM-routing neighbor aggregation + temporal blend.
// T=3, b=1, n=50000, d=64, m=16, K=4, dd=16.
// One 64-lane wave per (t, node); lane j owns element j. Factor k = j>>4.
// R2: pre-normalized x in d_ws + butterfly multi-reduce for logits
// (15 shuffles for all 16 dots; softmax over K batched: 2 exp/lane total).

constexpr int T = 3;
constexpr int N = 50000;
constexpr int D = 64;
constexpr int M = 16;
constexpr float EPS2 = 1e-24f;  // (1e-12)^2

__device__ __forceinline__ float g16sum(float v) {
    v += __shfl_xor(v, 1, 64);
    v += __shfl_xor(v, 2, 64);
    v += __shfl_xor(v, 4, 64);
    v += __shfl_xor(v, 8, 64);
    return v;
}

// Pass 1: per-factor L2 normalize, float4 per lane (4 lanes = one 16-dim factor).
__global__ __launch_bounds__(256) void norm_kernel(
    const float* __restrict__ x, float* __restrict__ xn)
{
    const int total = T * N * D / 4;
    int idx = blockIdx.x * blockDim.x + threadIdx.x;
    if (idx >= total) return;
    float4 v = ((const float4*)x)[idx];
    float s = v.x * v.x + v.y * v.y + v.z * v.z + v.w * v.w;
    s += __shfl_xor(s, 1, 64);
    s += __shfl_xor(s, 2, 64);
    float r = rsqrtf(fmaxf(s, EPS2));
    float4 o = make_float4(v.x * r, v.y * r, v.z * r, v.w * r);
    ((float4*)xn)[idx] = o;
}

template <bool PRENORM>
__global__ __launch_bounds__(256) void eaconv_agg(
    const float* __restrict__ xsrc,    // [T,N,D] normalized (PRENORM) or raw
    const int*   __restrict__ nbr_all, // [T,N,M]
    float*       __restrict__ out)     // [T,N,D] <- u_t (pre-blend)
{
    const int wave = (blockIdx.x * blockDim.x + threadIdx.x) >> 6;
    const int lane = threadIdx.x & 63;
    if (wave >= T * N) return;
    const int t = wave / N;
    const int i = wave - t * N;

    const float* x   = xsrc    + (size_t)t * N * D;
    const int*   nbr = nbr_all + ((size_t)t * N + i) * M;

    // own factors (normalized)
    float xk = x[(size_t)i * D + lane];
    if (!PRENORM) xk *= rsqrtf(fmaxf(g16sum(xk * xk), EPS2));

    // neighbor indices: lanes 0..15 load, broadcast via shuffle
    int myidx = nbr[lane & 15];

    // gather neighbor factors (already normalized if PRENORM)
    float z[M];
#pragma unroll
    for (int m = 0; m < M; ++m) {
        int j = __shfl(myidx, m, 64);
        float zv = ((unsigned)j < (unsigned)N) ? x[(size_t)j * D + lane] : 0.0f;
        if (!PRENORM) zv *= rsqrtf(fmaxf(g16sum(zv * zv), EPS2));
        z[m] = zv;
    }

    // ---- iteration 0: p = 1/K uniform ----
    float u = xk;
#pragma unroll
    for (int m = 0; m < M; ++m) u = fmaf(z[m], 0.25f, u);
    u *= rsqrtf(fmaxf(g16sum(u * u), EPS2));

    // ---- iterations 1..2 ----
#pragma unroll
    for (int it = 1; it < 3; ++it) {
        // per-lane partial products for all 16 neighbor dots
        float r[M];
#pragma unroll
        for (int m = 0; m < M; ++m) r[m] = z[m] * u;

        // butterfly multi-reduce: after strides 8,4,2,1 lane l of each
        // 16-group holds logit[m = l&15] for its factor k = lane>>4.
#pragma unroll
        for (int s = 8; s >= 1; s >>= 1) {
            const bool hi = (lane & s) != 0;
#pragma unroll
            for (int j = 0; j < s; ++j) {
                float a = hi ? r[j + s] : r[j];
                float b = hi ? r[j] : r[j + s];
                r[j] = a + __shfl_xor(b, s, 64);
            }
        }
        float logit = r[0];

        // softmax over the 4 factors (lanes xor 16, 32) — all 16 m at once
        float mx = logit;
        mx = fmaxf(mx, __shfl_xor(mx, 16, 64));
        mx = fmaxf(mx, __shfl_xor(mx, 32, 64));
        float e = __expf(logit - mx);
        float ssum = e;
        ssum += __shfl_xor(ssum, 16, 64);
        ssum += __shfl_xor(ssum, 32, 64);
        float w = e / ssum;  // weight for (m=lane&15, k=lane>>4)

        // unew = xk + sum_m z[m] * w[m, my k]; broadcast w from lane m of group
        float unew = xk;
#pragma unroll
        for (int m = 0; m < M; ++m) {
            float wm = __shfl(w, m, 16);  // lane m within each 16-lane segment
            unew = fmaf(z[m], wm, unew);
        }
        u = unew;
        if (it < 2)  // no normalize after last iteration
            u *= rsqrtf(fmaxf(g16sum(u * u), EPS2));
    }

    out[((size_t)t * N + i) * D + lane] = u;
}

// Temporal blend, closed form (sigmoid(0)=0.5, sigmoid(1)=0.7310585786):
//   e0 = u0
//   e1 = 0.25*e0 + 0.5*u1
//   e2 = (0.5*e0 + sig1*e1)*0.25 + 0.5*u2
__global__ __launch_bounds__(256) void eaconv_combine(float* __restrict__ out) {
    const int nd4 = N * D / 4;
    int idx = blockIdx.x * blockDim.x + threadIdx.x;
    if (idx >= nd4) return;
    float4* o = (float4*)out;
    float4 u0 = o[idx];
    float4 u1 = o[nd4 + idx];
    float4 u2 = o[2 * nd4 + idx];
    const float s1 = 0.7310585786300049f;
    float4 e1, e2;
    e1.x = 0.25f * u0.x + 0.5f * u1.x;
    e1.y = 0.25f * u0.y + 0.5f * u1.y;
    e1.z = 0.25f * u0.z + 0.5f * u1.z;
    e1.w = 0.25f * u0.w + 0.5f * u1.w;
    e2.x = (0.5f * u0.x + s1 * e1.x) * 0.25f + 0.5f * u2.x;
    e2.y = (0.5f * u0.y + s1 * e1.y) * 0.25f + 0.5f * u2.y;
    e2.z = (0.5f * u0.z + s1 * e1.z) * 0.25f + 0.5f * u2.z;
    e2.w = (0.5f * u0.w + s1 * e1.w) * 0.25f + 0.5f * u2.w;
    o[nd4 + idx] = e1;
    o[2 * nd4 + idx] = e2;
}

extern "C" void kernel_launch(void* const* d_in, const int* in_sizes, int n_in,
                              void* d_out, int out_size, void* d_ws, size_t ws_size,
                              hipStream_t stream) {
    const float* x_all = (const float*)d_in[0];
    const int*   nbrs  = (const int*)d_in[1];
    float*       out   = (float*)d_out;

    const size_t xn_bytes = sizeof(float) * (size_t)T * N * D;
    const int total_threads = T * N * 64;  // one wave per (t,node)

    if (ws_size >= xn_bytes) {
        float* xn = (float*)d_ws;
        norm_kernel<<<(T * N * D / 4 + 255) / 256, 256, 0, stream>>>(x_all, xn);
        eaconv_agg<true><<<(total_threads + 255) / 256, 256, 0, stream>>>(xn, nbrs, out);
    } else {
        eaconv_agg<false><<<(total_threads + 255) / 256, 256, 0, stream>>>(x_all, nbrs, out);
    }

    eaconv_combine<<<(N * D / 4 + 255) / 256, 256, 0, stream>>>(out);
}

// Round 3
// 245.182 us; speedup vs baseline: 3.1848x; 3.1848x over previous
//
#include <hip/hip_runtime.h>
#include <hip/hip_bf16.h>

// EAConv: EM-routing neighbor aggregation + temporal blend.
// T=3, b=1, n=50000, d=64, m=16, K=4, dd=16.
// R3 layout: one wave per (t,node); lane = (k,m) with m=lane&15 (neighbor),
// k=lane>>4 (factor). Each lane holds neighbor m's full 16-dim factor-k row
// in registers -> normalization and logit dots are IN-LANE (no shuffles),
// gather is a 2-deep load chain (nbr index, then 4 independent dwordx4).
// Cross-m aggregation uses DPP row_ror adds (VALU only, no DS pipe).

constexpr int T  = 3;
constexpr int N  = 50000;
constexpr int D  = 64;
constexpr int M  = 16;
constexpr int DD = 16;
constexpr float EPS2 = 1e-24f;  // (1e-12)^2

template <int CTRL>
__device__ __forceinline__ float dpp_add(float v) {
    // v + (v rotated within the 16-lane row); pure VALU (v_add_f32 dpp)
    int rot = __builtin_amdgcn_update_dpp(
        0, __float_as_int(v), CTRL, 0xF, 0xF, false);
    return v + __int_as_float(rot);
}

// sum over the 16 lanes of a row; result in every lane of the row
__device__ __forceinline__ float rowsum16(float v) {
    v = dpp_add<0x128>(v);  // row_ror:8
    v = dpp_add<0x124>(v);  // row_ror:4
    v = dpp_add<0x122>(v);  // row_ror:2
    v = dpp_add<0x121>(v);  // row_ror:1
    return v;
}

__global__ __launch_bounds__(256) void eaconv_agg(
    const float* __restrict__ x_all,   // [T,N,D] raw
    const int*   __restrict__ nbr_all, // [T,N,M]
    float*       __restrict__ out)     // [T,N,D] <- u_t (pre-blend)
{
    const int wave = (blockIdx.x * blockDim.x + threadIdx.x) >> 6;
    const int lane = threadIdx.x & 63;
    if (wave >= T * N) return;
    const int t = wave / N;
    const int i = wave - t * N;
    const int m = lane & 15;
    const int k = lane >> 4;

    const float* x = x_all + (size_t)t * N * D;

    // my neighbor index (lanes with the same m read the same value)
    int j = nbr_all[((size_t)t * N + i) * M + m];
    const bool valid = (unsigned)j < (unsigned)N;
    j = valid ? j : 0;

    // own factor row xk[0..15] (same addr across the 16 lanes of a row)
    const float4* xrow = (const float4*)(x + (size_t)i * D + k * DD);
    float4 a0 = xrow[0], a1 = xrow[1], a2 = xrow[2], a3 = xrow[3];

    // neighbor factor row (scattered across lanes, 4 independent 16B loads)
    const float4* zrow = (const float4*)(x + (size_t)j * D + k * DD);
    float4 b0 = zrow[0], b1 = zrow[1], b2 = zrow[2], b3 = zrow[3];

    float xk[DD] = {a0.x,a0.y,a0.z,a0.w, a1.x,a1.y,a1.z,a1.w,
                    a2.x,a2.y,a2.z,a2.w, a3.x,a3.y,a3.z,a3.w};
    float z[DD]  = {b0.x,b0.y,b0.z,b0.w, b1.x,b1.y,b1.z,b1.w,
                    b2.x,b2.y,b2.z,b2.w, b3.x,b3.y,b3.z,b3.w};

    // in-lane L2 normalize both rows (zero row for invalid neighbor)
    float sx = 0.f, sz = 0.f;
#pragma unroll
    for (int p = 0; p < DD; ++p) { sx = fmaf(xk[p], xk[p], sx);
                                   sz = fmaf(z[p],  z[p],  sz); }
    const float rx = __builtin_amdgcn_rsqf(fmaxf(sx, EPS2));
    float rz       = __builtin_amdgcn_rsqf(fmaxf(sz, EPS2));
    if (!valid) rz = 0.f;
#pragma unroll
    for (int p = 0; p < DD; ++p) { xk[p] *= rx; z[p] *= rz; }

    // ---- iteration 0: p = 1/K uniform ----
    float u[DD];
#pragma unroll
    for (int p = 0; p < DD; ++p) u[p] = fmaf(rowsum16(z[p]), 0.25f, xk[p]);
    {
        float s = 0.f;
#pragma unroll
        for (int p = 0; p < DD; ++p) s = fmaf(u[p], u[p], s);
        float r = __builtin_amdgcn_rsqf(fmaxf(s, EPS2));
#pragma unroll
        for (int p = 0; p < DD; ++p) u[p] *= r;
    }

    // ---- iterations 1..2 ----
#pragma unroll
    for (int it = 1; it < 3; ++it) {
        // logit[m][k]: in-lane dot over my 16-dim factor row
        float dot = 0.f;
#pragma unroll
        for (int p = 0; p < DD; ++p) dot = fmaf(z[p], u[p], dot);

        // softmax over the 4 factors (lanes xor 16, 32)
        float mx = fmaxf(dot, __shfl_xor(dot, 16, 64));
        mx = fmaxf(mx, __shfl_xor(mx, 32, 64));
        float e = __expf(dot - mx);
        float es = e + __shfl_xor(e, 16, 64);
        es += __shfl_xor(es, 32, 64);
        const float w = e * __builtin_amdgcn_rcpf(es);

        // u[p] = xk[p] + sum_m w[m,k] * z[m][k][p]  (rowsum over m)
#pragma unroll
        for (int p = 0; p < DD; ++p) u[p] = xk[p] + rowsum16(w * z[p]);

        if (it < 2) {  // no normalize after the last iteration
            float s = 0.f;
#pragma unroll
            for (int p = 0; p < DD; ++p) s = fmaf(u[p], u[p], s);
            float r = __builtin_amdgcn_rsqf(fmaxf(s, EPS2));
#pragma unroll
            for (int p = 0; p < DD; ++p) u[p] *= r;
        }
    }

    // store: u replicated across each row; lanes m=0..3 write one float4 each
    float* o = out + ((size_t)t * N + i) * D + k * DD;
    if (m == 0) ((float4*)o)[0] = make_float4(u[0],  u[1],  u[2],  u[3]);
    if (m == 1) ((float4*)o)[1] = make_float4(u[4],  u[5],  u[6],  u[7]);
    if (m == 2) ((float4*)o)[2] = make_float4(u[8],  u[9],  u[10], u[11]);
    if (m == 3) ((float4*)o)[3] = make_float4(u[12], u[13], u[14], u[15]);
}

// Temporal blend, closed form (sigmoid(0)=0.5, sigmoid(1)=0.7310585786):
//   e0 = u0
//   e1 = 0.25*e0 + 0.5*u1
//   e2 = (0.5*e0 + sig1*e1)*0.25 + 0.5*u2
__global__ __launch_bounds__(256) void eaconv_combine(float* __restrict__ out) {
    const int nd4 = N * D / 4;
    int idx = blockIdx.x * blockDim.x + threadIdx.x;
    if (idx >= nd4) return;
    float4* o = (float4*)out;
    float4 u0 = o[idx];
    float4 u1 = o[nd4 + idx];
    float4 u2 = o[2 * nd4 + idx];
    const float s1 = 0.7310585786300049f;
    float4 e1, e2;
    e1.x = 0.25f * u0.x + 0.5f * u1.x;
    e1.y = 0.25f * u0.y + 0.5f * u1.y;
    e1.z = 0.25f * u0.z + 0.5f * u1.z;
    e1.w = 0.25f * u0.w + 0.5f * u1.w;
    e2.x = (0.5f * u0.x + s1 * e1.x) * 0.25f + 0.5f * u2.x;
    e2.y = (0.5f * u0.y + s1 * e1.y) * 0.25f + 0.5f * u2.y;
    e2.z = (0.5f * u0.z + s1 * e1.z) * 0.25f + 0.5f * u2.z;
    e2.w = (0.5f * u0.w + s1 * e1.w) * 0.25f + 0.5f * u2.w;
    o[nd4 + idx] = e1;
    o[2 * nd4 + idx] = e2;
}

extern "C" void kernel_launch(void* const* d_in, const int* in_sizes, int n_in,
                              void* d_out, int out_size, void* d_ws, size_t ws_size,
                              hipStream_t stream) {
    const float* x_all = (const float*)d_in[0];
    const int*   nbrs  = (const int*)d_in[1];
    float*       out   = (float*)d_out;

    const int total_threads = T * N * 64;  // one wave per (t,node)
    eaconv_agg<<<(total_threads + 255) / 256, 256, 0, stream>>>(x_all, nbrs, out);
    eaconv_combine<<<(N * D / 4 + 255) / 256, 256, 0, stream>>>(out);
}